// Round 2
// baseline (106.407 us; speedup 1.0000x reference)
//
#include <hip/hip_runtime.h>

// Vanilla RNN B=4096 S=512 I=1 H=16 O=1 — serial-chain latency optimization.
//
// R14: SPLIT-DOT layout. Lane = (q, bs, r): r = tid&15 (h-row), bs = bit4
// (batch-sub, 2 batches/wave), q = bit5 (dot-product half). Each (batch,row)
// dot product is split across the lane pair {(0,bs,r),(1,bs,r)}: front is 8
// DPP fmacs (N=0..7) instead of 16. 2048 waves = 2 waves/SIMD; the two
// waves' serial chains are independent and overlap on the SIMD (unlike
// R11's within-wave packing, which serialized exactly 2x).
//
// Held-state trick making uniform DPP legal: lane (q,bs,r) holds
// G = g[(r+8q)%16]. Under row_ror:N (N=0..7) it reads g[(r-N+8q)%16], so
// q=0 covers cols {r-7..r}, q=1 covers {r+1..r+8} — disjoint, union = 16.
// Weights self-calibrate via ROTI on rq=(r+8q)&15 (same HW-permutation-
// faithful idiom as champion, R1/R7-validated).
//
// Reduce (partner = l^32, same bs, same r): p2 = mov(p);
// permlane32_swap(p2, p) leaves {(lo,lo),(hi,hi)} in the two regs in SOME
// order; p+p2 = p(l)+p(l^32) in every lane either way — no cndmask, no
// dependence on the swap convention. Then one row-masked
// v_mov_b32_dpp row_ror:8 row_mask:0xc rotates q=1 rows to s[(r+8)%16]
// BEFORE the tail, so tail output lands directly in held-rotated form.
// XP and bias are pre-halved (each q-lane seeds half; pair-sum restores).
//
// Hazard discipline (the R8/R9 corruption class): rcp -> s_nop 1 -> plain
// fmac before first DPP read of g (champion head, verbatim). s_nop 1
// (2 wait states) before v_permlane32_swap and before the masked mov_dpp
// (VALU-write -> lane-crossing-read needs 2 wait states on gfx9-class HW).
//
// g-trick: state g = 1/(2^s+1), h = 1-2g; rowsum(W_hh) folds into bias,
// -2*S2LE into weights; S2LE = 2*log2(e) pre-scales for exp2.
// Loads: R6 staged blocks, modulo-2 named buffers, no per-iter vmcnt drain.

#define S2LE 2.8853900817779268f  // 2*log2(e)

typedef float float4_ __attribute__((ext_vector_type(4)));

#define ROTI(v, N) __builtin_amdgcn_mov_dpp((v), 0x120 + (N), 0xF, 0xF, 0)
#define ROTF(v, N) __int_as_float(__builtin_amdgcn_mov_dpp(__float_as_int(v), 0x120 + (N), 0xF, 0xF, 0))

__global__ __launch_bounds__(64) void rnn_kernel(
    const float* __restrict__ x,
    const float* __restrict__ W_ih,
    const float* __restrict__ W_hh,
    const float* __restrict__ b_ih,
    const float* __restrict__ b_hh,
    const float* __restrict__ W_fc,
    const float* __restrict__ b_fc,
    float* __restrict__ out)
{
    const int li = (int)(threadIdx.x & 15u);          // h-row r
    const int bs = (int)((threadIdx.x >> 4) & 1u);    // batch-sub
    const int q  = (int)((threadIdx.x >> 5) & 1u);    // dot half
    const int b  = (int)(blockIdx.x * 2u + bs);

    const float* __restrict__ row = W_hh + li * 16;

    float sw = 0.0f;
#pragma unroll
    for (int j = 0; j < 16; ++j) sw += row[j];

    const float wsc = -2.0f * S2LE;

    // Self-calibrated split weights: w[N] = wsc * W[r][sigma_N(rq)],
    // rq = (r+8q)&15, sigma_N = the HW row_ror:N permutation. q=0 lanes
    // reproduce the champion's w0..w7 exactly.
    const int rq = (li + 8 * q) & 15;
    float w0 = wsc * row[rq];
    float w1 = wsc * row[ROTI(rq, 1)];
    float w2 = wsc * row[ROTI(rq, 2)];
    float w3 = wsc * row[ROTI(rq, 3)];
    float w4 = wsc * row[ROTI(rq, 4)];
    float w5 = wsc * row[ROTI(rq, 5)];
    float w6 = wsc * row[ROTI(rq, 6)];
    float w7 = wsc * row[ROTI(rq, 7)];

    // Pre-halved: each q-lane seeds XP/2; the q-pair sum restores XP.
    const float wih  = W_ih[li] * S2LE * 0.5f;
    const float bias = (b_ih[li] + b_hh[li] + sw) * S2LE * 0.5f;
    const float wfc  = q ? 0.0f : W_fc[li];   // epilogue uses q=0 rows only
    const float bfc  = b_fc[0];

    const float4_* __restrict__ xv = (const float4_*)(x + (size_t)b * 512);

    float g = 0.5f;  // h = 0 (any held rotation of the zero state)

    // One step: champion head (s_nop 1, tied a0=XP, plain fmac first), 8
    // DPP fmacs as 2 interleaved chains of 4, pair-sum via permlane32_swap
    // on a copy, row-masked ror:8 pre-shift for q=1, exp2-sigmoid tail.
#define STEP(XP) do { \
    float a0 = (XP), a1; \
    asm volatile( \
        "s_nop 1\n\t" \
        "v_fmac_f32 %0, %2, %3\n\t" \
        "v_mul_f32_dpp %1, %2, %7  row_ror:4 row_mask:0xf bank_mask:0xf\n\t" \
        "v_fmac_f32_dpp %0, %2, %4 row_ror:1 row_mask:0xf bank_mask:0xf\n\t" \
        "v_fmac_f32_dpp %1, %2, %8 row_ror:5 row_mask:0xf bank_mask:0xf\n\t" \
        "v_fmac_f32_dpp %0, %2, %5 row_ror:2 row_mask:0xf bank_mask:0xf\n\t" \
        "v_fmac_f32_dpp %1, %2, %9 row_ror:6 row_mask:0xf bank_mask:0xf\n\t" \
        "v_fmac_f32_dpp %0, %2, %6 row_ror:3 row_mask:0xf bank_mask:0xf\n\t" \
        "v_fmac_f32_dpp %1, %2, %10 row_ror:7 row_mask:0xf bank_mask:0xf\n\t" \
        "v_add_f32 %0, %0, %1\n\t"                    /* p = a0+a1        */ \
        "v_mov_b32 %1, %0\n\t"                        /* copy for swap    */ \
        "s_nop 1\n\t" \
        "v_permlane32_swap_b32 %1, %0\n\t"            /* halves exchanged */ \
        "v_add_f32 %0, %0, %1\n\t"                    /* u = p + p(l^32)  */ \
        "s_nop 1\n\t" \
        "v_mov_b32_dpp %0, %0 row_ror:8 row_mask:0xc bank_mask:0xf\n\t" \
        : "+v"(a0), "=&v"(a1) \
        : "v"(g), \
          "v"(w0), "v"(w1), "v"(w2), "v"(w3), \
          "v"(w4), "v"(w5), "v"(w6), "v"(w7)); \
    float e_ = __builtin_amdgcn_exp2f(a0); \
    g = __builtin_amdgcn_rcpf(e_ + 1.0f); \
} while (0)

// 16 recurrent steps from a 4-x-float4 staged block.
#define BLOCK(BUF) do { \
    _Pragma("unroll") \
    for (int j = 0; j < 4; ++j) { \
        STEP(fmaf((BUF)[j][0], wih, bias)); \
        STEP(fmaf((BUF)[j][1], wih, bias)); \
        STEP(fmaf((BUF)[j][2], wih, bias)); \
        STEP(fmaf((BUF)[j][3], wih, bias)); \
    } \
} while (0)

    float4_ bufA[4], bufB[4];
#pragma unroll
    for (int j = 0; j < 4; ++j) bufA[j] = xv[j];  // block 0

    // Unroll-2 modulo pipeline over 32 blocks of 16 timesteps (R6): loads
    // issue one full block ahead; no register rotation, no per-iter drain.
#pragma unroll 1
    for (int i = 0; i < 32; i += 2) {
#pragma unroll
        for (int j = 0; j < 4; ++j) bufB[j] = xv[(4 * (i + 1) + j) & 127];
        BLOCK(bufA);
#pragma unroll
        for (int j = 0; j < 4; ++j) bufA[j] = xv[(4 * (i + 2) + j) & 127];
        BLOCK(bufB);
    }
#undef BLOCK
#undef STEP

    // out[b] = sum_r wfc_r * h_r + bfc, h = 1-2g. q=0 rows hold g_r
    // unrotated and wfc is zeroed on q=1, so the in-row rotation tree
    // alone produces the full sum in every q=0 lane.
    float p = fmaf(-2.0f * wfc, g, wfc);
    p += ROTF(p, 8);
    p += ROTF(p, 4);
    p += ROTF(p, 2);
    p += ROTF(p, 1);
    if ((threadIdx.x & 47u) == 0) out[b] = p + bfc;
}

extern "C" void kernel_launch(void* const* d_in, const int* in_sizes, int n_in,
                              void* d_out, int out_size, void* d_ws, size_t ws_size,
                              hipStream_t stream) {
    const float* x    = (const float*)d_in[0];
    const float* W_ih = (const float*)d_in[1];
    const float* W_hh = (const float*)d_in[2];
    const float* b_ih = (const float*)d_in[3];
    const float* b_hh = (const float*)d_in[4];
    const float* W_fc = (const float*)d_in[5];
    const float* b_fc = (const float*)d_in[6];
    float* out = (float*)d_out;

    rnn_kernel<<<2048, 64, 0, stream>>>(x, W_ih, W_hh, b_ih, b_hh, W_fc, b_fc, out);
}